// Round 1
// baseline (1315.631 us; speedup 1.0000x reference)
//
#include <hip/hip_runtime.h>
#include <math.h>

// Problem geometry (fixed per reference setup_inputs)
#define WD 192
#define HD 192
#define DD 96
#define VOL (DD*HD*WD)          // 3,538,944 voxels per volume
#define HB 4                    // rows of H per block
#define NWAVE ((WD*HB)/64)      // 12 waves per block

// source modes for on-the-fly evaluation
#define SRC_BUF  0
#define SRC_PRED 1   // p1 = sigmoid(x1 - x0) from y_pred[b]
#define SRC_TRUE 2   // oh1 = (y_true[b] == 1)

template<int SRC>
__device__ __forceinline__ float src_eval(const float* buf, const float* yp,
                                          const int* yt, int b, int idx) {
    if constexpr (SRC == SRC_BUF) {
        return buf[idx];
    } else if constexpr (SRC == SRC_PRED) {
        const float* base = yp + (size_t)b * (2 * (size_t)VOL);
        float x0 = base[idx];
        float x1 = base[(size_t)VOL + idx];
        return 1.0f / (1.0f + __expf(x0 - x1));   // softmax fg channel, C=2
    } else {
        return (yt[(size_t)b * VOL + idx] == 1) ? 1.0f : 0.0f;
    }
}

// ---------- pass E1: e1 = erode7(source) ----------
template<int SRC>
__global__ void erode_kernel(const float* src, const float* __restrict__ yp,
                             const int* __restrict__ yt, int b, float* out) {
    int w = threadIdx.x;
    int hb = blockIdx.x % (HD / HB);
    int d  = blockIdx.x / (HD / HB);
    int h  = hb * HB + threadIdx.y;
    int idx = (d * HD + h) * WD + w;

    float v = src_eval<SRC>(src, yp, yt, b, idx);
    if (w > 0)      v = fminf(v, src_eval<SRC>(src, yp, yt, b, idx - 1));
    if (w < WD - 1) v = fminf(v, src_eval<SRC>(src, yp, yt, b, idx + 1));
    if (h > 0)      v = fminf(v, src_eval<SRC>(src, yp, yt, b, idx - WD));
    if (h < HD - 1) v = fminf(v, src_eval<SRC>(src, yp, yt, b, idx + WD));
    if (d > 0)      v = fminf(v, src_eval<SRC>(src, yp, yt, b, idx - HD * WD));
    if (d < DD - 1) v = fminf(v, src_eval<SRC>(src, yp, yt, b, idx + HD * WD));
    out[idx] = v;
}

// ---------- passes U1..U4: delta = relu(prev - dilate27(e)); skel update;
//            fused enext = erode7(e)  (except FINAL, which reduces) ----------
// prev/enext may alias (point access only at own idx) -> NO __restrict__ on them.
template<int PSRC, bool FIRST, bool FINAL, int WSRC>
__global__ void update_kernel(const float* prev, const float* __restrict__ e,
                              float* skel, float* enext,
                              const float* __restrict__ yp, const int* __restrict__ yt,
                              int b, double* acc) {
    int w = threadIdx.x;
    int hb = blockIdx.x % (HD / HB);
    int d  = blockIdx.x / (HD / HB);
    int h  = hb * HB + threadIdx.y;
    int idx = (d * HD + h) * WD + w;

    // dilate: 27-point max over e (skip out-of-bounds == pad with -inf)
    int dz0 = (d > 0) ? -1 : 0, dz1 = (d < DD - 1) ? 1 : 0;
    int dy0 = (h > 0) ? -1 : 0, dy1 = (h < HD - 1) ? 1 : 0;
    int dx0 = (w > 0) ? -1 : 0, dx1 = (w < WD - 1) ? 1 : 0;
    float m = -INFINITY;
    for (int dz = dz0; dz <= dz1; ++dz)
        for (int dy = dy0; dy <= dy1; ++dy)
            for (int dx = dx0; dx <= dx1; ++dx)
                m = fmaxf(m, e[idx + (dz * HD + dy) * WD + dx]);

    float pv    = src_eval<PSRC>(prev, yp, yt, b, idx);
    float delta = fmaxf(pv - m, 0.0f);
    float s     = FIRST ? 0.0f : skel[idx];
    float sn    = s + fmaxf(delta - s * delta, 0.0f);

    if constexpr (!FINAL) {
        skel[idx] = sn;
        // fused erode7(e) -> enext (reuses stencil lines already in cache)
        float v = e[idx];
        if (w > 0)      v = fminf(v, e[idx - 1]);
        if (w < WD - 1) v = fminf(v, e[idx + 1]);
        if (h > 0)      v = fminf(v, e[idx - WD]);
        if (h < HD - 1) v = fminf(v, e[idx + WD]);
        if (d > 0)      v = fminf(v, e[idx - HD * WD]);
        if (d < DD - 1) v = fminf(v, e[idx + HD * WD]);
        enext[idx] = v;
    } else {
        // final skel value: reduce sum(skel) and sum(skel * weight)
        float wgt = src_eval<WSRC>(nullptr, yp, yt, b, idx);
        float a0 = sn, a1 = sn * wgt;
        for (int off = 32; off > 0; off >>= 1) {
            a0 += __shfl_down(a0, off);
            a1 += __shfl_down(a1, off);
        }
        __shared__ float s0[NWAVE], s1[NWAVE];
        int tid = threadIdx.y * WD + threadIdx.x;
        int wid = tid >> 6, lane = tid & 63;
        if (lane == 0) { s0[wid] = a0; s1[wid] = a1; }
        __syncthreads();
        if (tid == 0) {
            float t0 = 0.f, t1 = 0.f;
            for (int i = 0; i < NWAVE; ++i) { t0 += s0[i]; t1 += s1[i]; }
            atomicAdd(acc + 0, (double)t0);
            atomicAdd(acc + 1, (double)t1);
        }
    }
}

// ---------- dice sums: sum(p1), sum(oh1), sum(oh1*p1) over both batches ----------
__global__ void dice_sums_kernel(const float* __restrict__ yp, const int* __restrict__ yt,
                                 double* __restrict__ acc) {
    const int total = 2 * VOL;
    float sp = 0.f, so = 0.f, si = 0.f;
    for (int i = blockIdx.x * blockDim.x + threadIdx.x; i < total;
         i += gridDim.x * blockDim.x) {
        int b = (i >= VOL) ? 1 : 0;
        int r = i - b * VOL;
        const float* base = yp + (size_t)b * (2 * (size_t)VOL);
        float x0 = base[r];
        float x1 = base[(size_t)VOL + r];
        float p1 = 1.0f / (1.0f + __expf(x0 - x1));
        float oh = (yt[i] == 1) ? 1.0f : 0.0f;
        sp += p1; so += oh; si += oh * p1;
    }
    for (int off = 32; off > 0; off >>= 1) {
        sp += __shfl_down(sp, off);
        so += __shfl_down(so, off);
        si += __shfl_down(si, off);
    }
    __shared__ float s0[4], s1[4], s2[4];
    int tid = threadIdx.x, wid = tid >> 6, lane = tid & 63;
    if (lane == 0) { s0[wid] = sp; s1[wid] = so; s2[wid] = si; }
    __syncthreads();
    if (tid == 0) {
        float t0 = 0.f, t1 = 0.f, t2 = 0.f;
        for (int i = 0; i < 4; ++i) { t0 += s0[i]; t1 += s1[i]; t2 += s2[i]; }
        atomicAdd(acc + 0, (double)t0);   // sum p1
        atomicAdd(acc + 1, (double)t1);   // sum oh1
        atomicAdd(acc + 2, (double)t2);   // inter
    }
}

__global__ void zero_accum_kernel(double* acc) {
    if (threadIdx.x < 8) acc[threadIdx.x] = 0.0;
}

__global__ void finalize_kernel(const double* __restrict__ acc, float* __restrict__ out) {
    double sum_p = acc[0], sum_oh = acc[1], inter = acc[2];
    double sp_s = acc[3], sp_w = acc[4];   // skel_pred: sum, sum*oh
    double st_s = acc[5], st_w = acc[6];   // skel_true: sum, sum*p
    double dice  = 1.0 - (2.0 * inter + 1.0) / (sum_oh + sum_p + 1.0);
    double tprec = (sp_w + 1.0) / (sp_s + 1.0);
    double tsens = (st_w + 1.0) / (st_s + 1.0);
    double cl    = 1.0 - 2.0 * (tprec * tsens) / (tprec + tsens);
    out[0] = (float)(dice + cl);
}

extern "C" void kernel_launch(void* const* d_in, const int* in_sizes, int n_in,
                              void* d_out, int out_size, void* d_ws, size_t ws_size,
                              hipStream_t stream) {
    const float* y_pred = (const float*)d_in[0];
    const int*   y_true = (const int*)d_in[1];
    float* out = (float*)d_out;

    char* ws = (char*)d_ws;
    double* acc = (double*)ws;                       // 8 doubles
    float* skel = (float*)(ws + 256);
    float* eA   = skel + VOL;
    float* eB   = eA + VOL;                          // total ~42.5 MB

    zero_accum_kernel<<<1, 64, 0, stream>>>(acc);
    dice_sums_kernel<<<2048, 256, 0, stream>>>(y_pred, y_true, acc);

    dim3 blk(WD, HB);                // 768 threads = 12 waves
    dim3 grd((HD / HB) * DD);        // 4608 blocks

    for (int b = 0; b < 2; ++b) {
        // ---- skel_pred chain on p1[b]; final weight = oh1 -> acc[3],acc[4]
        erode_kernel<SRC_PRED><<<grd, blk, 0, stream>>>(nullptr, y_pred, y_true, b, eA);
        update_kernel<SRC_PRED, true,  false, SRC_BUF ><<<grd, blk, 0, stream>>>(nullptr, eA, skel, eB, y_pred, y_true, b, nullptr);
        update_kernel<SRC_BUF,  false, false, SRC_BUF ><<<grd, blk, 0, stream>>>(eA, eB, skel, eA, y_pred, y_true, b, nullptr);
        update_kernel<SRC_BUF,  false, false, SRC_BUF ><<<grd, blk, 0, stream>>>(eB, eA, skel, eB, y_pred, y_true, b, nullptr);
        update_kernel<SRC_BUF,  false, true,  SRC_TRUE><<<grd, blk, 0, stream>>>(eA, eB, skel, nullptr, y_pred, y_true, b, acc + 3);

        // ---- skel_true chain on oh1[b]; final weight = p1 -> acc[5],acc[6]
        erode_kernel<SRC_TRUE><<<grd, blk, 0, stream>>>(nullptr, y_pred, y_true, b, eA);
        update_kernel<SRC_TRUE, true,  false, SRC_BUF ><<<grd, blk, 0, stream>>>(nullptr, eA, skel, eB, y_pred, y_true, b, nullptr);
        update_kernel<SRC_BUF,  false, false, SRC_BUF ><<<grd, blk, 0, stream>>>(eA, eB, skel, eA, y_pred, y_true, b, nullptr);
        update_kernel<SRC_BUF,  false, false, SRC_BUF ><<<grd, blk, 0, stream>>>(eB, eA, skel, eB, y_pred, y_true, b, nullptr);
        update_kernel<SRC_BUF,  false, true,  SRC_PRED><<<grd, blk, 0, stream>>>(eA, eB, skel, nullptr, y_pred, y_true, b, acc + 5);
    }

    finalize_kernel<<<1, 1, 0, stream>>>(acc, out);
}

// Round 2
// 419.449 us; speedup vs baseline: 3.1366x; 3.1366x over previous
//
#include <hip/hip_runtime.h>
#include <math.h>

// Problem geometry (fixed per reference setup_inputs)
#define WD 192
#define HD 192
#define DD 96
#define VOL (DD*HD*WD)          // 3,538,944 voxels per volume

#define PINF INFINITY
#define NINF (-INFINITY)

// source modes for on-the-fly evaluation
#define SRC_BUF  0
#define SRC_PRED 1   // p1 = sigmoid(x1 - x0) from y_pred[b]
#define SRC_TRUE 2   // oh1 = (y_true[b] == 1)

__device__ __forceinline__ float fmin3(float a, float b, float c) { return fminf(a, fminf(b, c)); }
__device__ __forceinline__ float fmax3(float a, float b, float c) { return fmaxf(a, fmaxf(b, c)); }

template<int SRC>
__device__ __forceinline__ float ld1(const float* buf, const float* yp,
                                     const int* yt, int b, int idx) {
    if constexpr (SRC == SRC_BUF) {
        return buf[idx];
    } else if constexpr (SRC == SRC_PRED) {
        const float* base = yp + (size_t)b * (2 * (size_t)VOL);
        float x0 = base[idx];
        float x1 = base[(size_t)VOL + idx];
        return 1.0f / (1.0f + __expf(x0 - x1));   // softmax fg channel, C=2
    } else {
        return (yt[(size_t)b * VOL + idx] == 1) ? 1.0f : 0.0f;
    }
}

template<int SRC>
__device__ __forceinline__ float4 ld4(const float* buf, const float* yp,
                                      const int* yt, int b, int idx) {
    if constexpr (SRC == SRC_BUF) {
        return *(const float4*)(buf + idx);
    } else if constexpr (SRC == SRC_PRED) {
        const float* base = yp + (size_t)b * (2 * (size_t)VOL);
        float4 a = *(const float4*)(base + idx);
        float4 c = *(const float4*)(base + (size_t)VOL + idx);
        float4 r;
        r.x = 1.0f / (1.0f + __expf(a.x - c.x));
        r.y = 1.0f / (1.0f + __expf(a.y - c.y));
        r.z = 1.0f / (1.0f + __expf(a.z - c.z));
        r.w = 1.0f / (1.0f + __expf(a.w - c.w));
        return r;
    } else {
        int4 t = *(const int4*)(yt + (size_t)b * VOL + idx);
        float4 r;
        r.x = (t.x == 1) ? 1.0f : 0.0f;
        r.y = (t.y == 1) ? 1.0f : 0.0f;
        r.z = (t.z == 1) ? 1.0f : 0.0f;
        r.w = (t.w == 1) ? 1.0f : 0.0f;
        return r;
    }
}

__device__ __forceinline__ float4 fmin4(float4 a, float4 b) {
    return make_float4(fminf(a.x,b.x), fminf(a.y,b.y), fminf(a.z,b.z), fminf(a.w,b.w));
}

// ---------- erode7 pass, float4-vectorized ----------
template<int SRC>
__global__ void __launch_bounds__(256)
erode4_kernel(const float* src, const float* __restrict__ yp,
              const int* __restrict__ yt, int b, float* __restrict__ out) {
    int i = blockIdx.x * blockDim.x + threadIdx.x;       // over VOL/4, exact grid
    int w4 = i % (WD/4);
    int rest = i / (WD/4);
    int h = rest % HD;
    int d = rest / HD;
    int idx = i * 4;

    float4 c = ld4<SRC>(src, yp, yt, b, idx);
    float lf = (w4 > 0)        ? ld1<SRC>(src, yp, yt, b, idx - 1) : PINF;
    float rt = (w4 < WD/4 - 1) ? ld1<SRC>(src, yp, yt, b, idx + 4) : PINF;

    float4 m;
    m.x = fmin3(lf,  c.x, c.y);
    m.y = fmin3(c.x, c.y, c.z);
    m.z = fmin3(c.y, c.z, c.w);
    m.w = fmin3(c.z, c.w, rt);

    float4 inf4 = make_float4(PINF, PINF, PINF, PINF);
    float4 up = (h > 0)      ? ld4<SRC>(src, yp, yt, b, idx - WD) : inf4;
    float4 dn = (h < HD - 1) ? ld4<SRC>(src, yp, yt, b, idx + WD) : inf4;
    float4 zu = (d > 0)      ? ld4<SRC>(src, yp, yt, b, idx - HD*WD) : inf4;
    float4 zd = (d < DD - 1) ? ld4<SRC>(src, yp, yt, b, idx + HD*WD) : inf4;
    m = fmin4(m, up); m = fmin4(m, dn); m = fmin4(m, zu); m = fmin4(m, zd);

    *(float4*)(out + idx) = m;
}

// ---------- fused cl-dice kernel: per volume, z-walk plane pipeline ----------
// Computes, per output voxel z: d_i = dilate27(e_{i+1}) for i=0..3 (e4 = erode(e3)
// computed on the fly), delta_i = relu(e_i - d_i), skel = 1 - prod(1-delta_i),
// and reduces sum(skel), sum(skel*weight). No skel/e4 volumes materialized.
// Tile: input 32x16 cols (block 512 thr), output 28x12, halo 2. Slabs along z.
#define TSX 32
#define TSY 16
#define OSX 28
#define OSY 12
#define NSLAB 8
#define SLABZ (DD/NSLAB)

template<int SSRC, int WSRC>
__global__ void __launch_bounds__(512)
fused_cldice_kernel(const float* __restrict__ e1v, const float* __restrict__ e2v,
                    const float* __restrict__ e3v,
                    const float* __restrict__ yp, const int* __restrict__ yt,
                    int b, double* __restrict__ acc) {
    const int x = threadIdx.x, y = threadIdx.y;
    const int tw = blockIdx.x % (WD/OSX + 0);      // 192/28 -> 7 tiles (overhang clipped)
    const int th = blockIdx.x / 7;
    const int slab = blockIdx.y;
    const int w = tw * OSX + x - 2;
    const int h = th * OSY + y - 2;
    const bool cv = (w >= 0 && w < WD && h >= 0 && h < HD);
    const int z0 = slab * SLABZ, z1 = z0 + SLABZ;
    const bool inner = (x >= 2 && x < 2 + OSX && y >= 2 && y < 2 + OSY && w < WD && h < HD);

    __shared__ float rm0[TSY][TSX], rm1[TSY][TSX], rm2[TSY][TSX],
                     e3p[TSY][TSX], rm3[TSY][TSX];

    // register rings along z
    float m20a = NINF, m20b = NINF, m21a = NINF, m21b = NINF;
    float m22a = NINF, m22b = NINF, m23a = NINF, m23b = NINF;
    float e3a = PINF, e3b = PINF;     // own-column e3 (min-sentineled), planes Z-2, Z-1
    float ce3p = PINF;                // c_e3[Z-1]
    float e1p = 0.f, e2p = 0.f;       // own e1,e2 at plane Z-1
    float pap = 1.f;                  // P_a[Z-2] = (1-d0)(1-d1)(1-d2)
    float sum_s = 0.f, sum_sw = 0.f;

    for (int Z = z0 - 2; Z <= z1 + 1; ++Z) {
        const bool zv = (Z >= 0 && Z < DD);
        const bool lv = cv && zv;
        const int idx = (Z * HD + h) * WD + w;
        float g1  = lv ? e1v[idx] : NINF;
        float g2  = lv ? e2v[idx] : NINF;
        float g3r = lv ? e3v[idx] : 0.f;
        float g3x = lv ? g3r : NINF;      // for max (dilate) paths
        float g3n = lv ? g3r : PINF;      // for min (erode) paths

        __syncthreads();   // protect previous iteration's LDS reads
        // row min/max over W via shfl (width 32 = tile row)
        float r0 = fmax3(__shfl_up(g1, 1, 32),  g1,  __shfl_down(g1, 1, 32));
        float r1 = fmax3(__shfl_up(g2, 1, 32),  g2,  __shfl_down(g2, 1, 32));
        float r2 = fmax3(__shfl_up(g3x, 1, 32), g3x, __shfl_down(g3x, 1, 32));
        float rn = fmin3(__shfl_up(g3n, 1, 32), g3n, __shfl_down(g3n, 1, 32));
        rm0[y][x] = r0; rm1[y][x] = r1; rm2[y][x] = r2; e3p[y][x] = g3n;
        __syncthreads();
        // 3x3 in-plane max (m2_i) / cross-min (c_e3)
        float m20c = fmax3(r0, (y > 0) ? rm0[y-1][x] : NINF, (y < TSY-1) ? rm0[y+1][x] : NINF);
        float m21c = fmax3(r1, (y > 0) ? rm1[y-1][x] : NINF, (y < TSY-1) ? rm1[y+1][x] : NINF);
        float m22c = fmax3(r2, (y > 0) ? rm2[y-1][x] : NINF, (y < TSY-1) ? rm2[y+1][x] : NINF);
        float ce3  = fmin3(rn, (y > 0) ? e3p[y-1][x] : PINF, (y < TSY-1) ? e3p[y+1][x] : PINF);
        // e4[Z-1] = min(c_e3[Z-1], e3[Z-2], e3[Z])
        float e4 = fmin3(ce3p, e3a, g3n);
        const bool zv1 = (Z-1 >= 0 && Z-1 < DD);
        float e4x = (cv && zv1) ? e4 : NINF;
        float r3 = fmax3(__shfl_up(e4x, 1, 32), e4x, __shfl_down(e4x, 1, 32));
        rm3[y][x] = r3;
        __syncthreads();
        float m23c = fmax3(r3, (y > 0) ? rm3[y-1][x] : NINF, (y < TSY-1) ? rm3[y+1][x] : NINF);

        // ---- outputs ----
        float pac = 1.f;
        const int zo1 = Z - 1;                 // delta0,1,2 plane
        if (inner && zo1 >= z0 && zo1 < z1) {
            float d0 = fmax3(m20a, m20b, m20c);
            float d1 = fmax3(m21a, m21b, m21c);
            float d2 = fmax3(m22a, m22b, m22c);
            float s  = ld1<SSRC>(nullptr, yp, yt, b, (zo1 * HD + h) * WD + w);
            float t0 = fmaxf(s   - d0, 0.f);
            float t1 = fmaxf(e1p - d1, 0.f);
            float t2 = fmaxf(e2p - d2, 0.f);
            pac = (1.f - t0) * (1.f - t1) * (1.f - t2);
        }
        const int zo2 = Z - 2;                 // delta3 + finalize plane
        if (inner && zo2 >= z0 && zo2 < z1) {
            float d3 = fmax3(m23a, m23b, m23c);
            float t3 = fmaxf(e3a - d3, 0.f);
            float skel = 1.f - pap * (1.f - t3);
            float wgt = ld1<WSRC>(nullptr, yp, yt, b, (zo2 * HD + h) * WD + w);
            sum_s  += skel;
            sum_sw += skel * wgt;
        }
        // rotate rings
        m20a = m20b; m20b = m20c;  m21a = m21b; m21b = m21c;
        m22a = m22b; m22b = m22c;  m23a = m23b; m23b = m23c;
        e3a = e3b;  e3b = g3n;
        ce3p = ce3;
        e1p = g1;   e2p = g2;
        pap = pac;
    }

    // block reduction -> global double accumulators
    for (int off = 32; off > 0; off >>= 1) {
        sum_s  += __shfl_down(sum_s,  off);
        sum_sw += __shfl_down(sum_sw, off);
    }
    __shared__ float s0[8], s1[8];
    int tid = y * TSX + x;
    int wid = tid >> 6, lane = tid & 63;
    if (lane == 0) { s0[wid] = sum_s; s1[wid] = sum_sw; }
    __syncthreads();
    if (tid == 0) {
        float t0 = 0.f, t1 = 0.f;
        for (int i = 0; i < 8; ++i) { t0 += s0[i]; t1 += s1[i]; }
        atomicAdd(acc + 0, (double)t0);
        atomicAdd(acc + 1, (double)t1);
    }
}

// ---------- dice sums: sum(p1), sum(oh1), sum(oh1*p1) over both batches ----------
__global__ void dice_sums_kernel(const float* __restrict__ yp, const int* __restrict__ yt,
                                 double* __restrict__ acc) {
    const int total = 2 * VOL;
    float sp = 0.f, so = 0.f, si = 0.f;
    for (int i = blockIdx.x * blockDim.x + threadIdx.x; i < total;
         i += gridDim.x * blockDim.x) {
        int b = (i >= VOL) ? 1 : 0;
        int r = i - b * VOL;
        const float* base = yp + (size_t)b * (2 * (size_t)VOL);
        float x0 = base[r];
        float x1 = base[(size_t)VOL + r];
        float p1 = 1.0f / (1.0f + __expf(x0 - x1));
        float oh = (yt[i] == 1) ? 1.0f : 0.0f;
        sp += p1; so += oh; si += oh * p1;
    }
    for (int off = 32; off > 0; off >>= 1) {
        sp += __shfl_down(sp, off);
        so += __shfl_down(so, off);
        si += __shfl_down(si, off);
    }
    __shared__ float s0[4], s1[4], s2[4];
    int tid = threadIdx.x, wid = tid >> 6, lane = tid & 63;
    if (lane == 0) { s0[wid] = sp; s1[wid] = so; s2[wid] = si; }
    __syncthreads();
    if (tid == 0) {
        float t0 = 0.f, t1 = 0.f, t2 = 0.f;
        for (int i = 0; i < 4; ++i) { t0 += s0[i]; t1 += s1[i]; t2 += s2[i]; }
        atomicAdd(acc + 0, (double)t0);
        atomicAdd(acc + 1, (double)t1);
        atomicAdd(acc + 2, (double)t2);
    }
}

__global__ void zero_accum_kernel(double* acc) {
    if (threadIdx.x < 8) acc[threadIdx.x] = 0.0;
}

__global__ void finalize_kernel(const double* __restrict__ acc, float* __restrict__ out) {
    double sum_p = acc[0], sum_oh = acc[1], inter = acc[2];
    double sp_s = acc[3], sp_w = acc[4];   // skel_pred: sum, sum*oh
    double st_s = acc[5], st_w = acc[6];   // skel_true: sum, sum*p
    double dice  = 1.0 - (2.0 * inter + 1.0) / (sum_oh + sum_p + 1.0);
    double tprec = (sp_w + 1.0) / (sp_s + 1.0);
    double tsens = (st_w + 1.0) / (st_s + 1.0);
    double cl    = 1.0 - 2.0 * (tprec * tsens) / (tprec + tsens);
    out[0] = (float)(dice + cl);
}

extern "C" void kernel_launch(void* const* d_in, const int* in_sizes, int n_in,
                              void* d_out, int out_size, void* d_ws, size_t ws_size,
                              hipStream_t stream) {
    const float* y_pred = (const float*)d_in[0];
    const int*   y_true = (const int*)d_in[1];
    float* out = (float*)d_out;

    char* ws = (char*)d_ws;
    double* acc = (double*)ws;                       // 8 doubles
    float* eA = (float*)(ws + 256);
    float* eB = eA + VOL;
    float* eC = eB + VOL;                            // total ~42.5 MB (same as round 1)

    zero_accum_kernel<<<1, 64, 0, stream>>>(acc);
    dice_sums_kernel<<<2048, 256, 0, stream>>>(y_pred, y_true, acc);

    const int EG = VOL / 4 / 256;                    // 3456 blocks, exact
    dim3 fblk(TSX, TSY);                             // 512 threads
    dim3 fgrd(7 * (HD / OSY), NSLAB);                // 112 x 8

    for (int b = 0; b < 2; ++b) {
        // ---- skel_pred chain on p1[b]; weight = oh1 -> acc[3],acc[4]
        erode4_kernel<SRC_PRED><<<EG, 256, 0, stream>>>(nullptr, y_pred, y_true, b, eA);
        erode4_kernel<SRC_BUF ><<<EG, 256, 0, stream>>>(eA, y_pred, y_true, b, eB);
        erode4_kernel<SRC_BUF ><<<EG, 256, 0, stream>>>(eB, y_pred, y_true, b, eC);
        fused_cldice_kernel<SRC_PRED, SRC_TRUE><<<fgrd, fblk, 0, stream>>>(
            eA, eB, eC, y_pred, y_true, b, acc + 3);

        // ---- skel_true chain on oh1[b]; weight = p1 -> acc[5],acc[6]
        erode4_kernel<SRC_TRUE><<<EG, 256, 0, stream>>>(nullptr, y_pred, y_true, b, eA);
        erode4_kernel<SRC_BUF ><<<EG, 256, 0, stream>>>(eA, y_pred, y_true, b, eB);
        erode4_kernel<SRC_BUF ><<<EG, 256, 0, stream>>>(eB, y_pred, y_true, b, eC);
        fused_cldice_kernel<SRC_TRUE, SRC_PRED><<<fgrd, fblk, 0, stream>>>(
            eA, eB, eC, y_pred, y_true, b, acc + 5);
    }

    finalize_kernel<<<1, 1, 0, stream>>>(acc, out);
}

// Round 3
// 366.165 us; speedup vs baseline: 3.5930x; 1.1455x over previous
//
#include <hip/hip_runtime.h>
#include <math.h>

// Problem geometry (fixed per reference setup_inputs)
#define WD 192
#define HD 192
#define DD 96
#define VOL (DD*HD*WD)          // 3,538,944 voxels per volume

#define PINF INFINITY
#define NINF (-INFINITY)

#define SRC_PRED 1   // p1 = sigmoid(x1 - x0) from y_pred[b]
#define SRC_TRUE 2   // oh1 = (y_true[b] == 1)

#define TSX 32
#define TSY 16
#define NSLAB 8
#define SLABZ (DD/NSLAB)

// erode123 tiling: halo 3 -> inner 26x10
#define EOX 26
#define EOY 10
#define ETW 8      // ceil(192/26)
#define ETH 20     // ceil(192/10)

// fused tiling: halo 2 -> inner 28x12
#define OSX 28
#define OSY 12

__device__ __forceinline__ float fmin3(float a, float b, float c) { return fminf(a, fminf(b, c)); }
__device__ __forceinline__ float fmax3(float a, float b, float c) { return fmaxf(a, fmaxf(b, c)); }

template<int SRC>
__device__ __forceinline__ float xform(float v) {
    if constexpr (SRC == SRC_PRED) return 1.0f / (1.0f + __expf(-v));  // sigmoid (logit->p)
    else return v;
}

template<int SRC>
__device__ __forceinline__ float ld_center(const float* yp, const int* yt, int b, int idx) {
    if constexpr (SRC == SRC_PRED) {
        const float* base = yp + (size_t)b * (2 * (size_t)VOL);
        return 1.0f / (1.0f + __expf(base[idx] - base[(size_t)VOL + idx]));
    } else {
        return (yt[(size_t)b * VOL + idx] == 1) ? 1.0f : 0.0f;
    }
}

// ---------- erode123: plane-pipelined triple erode, writes e1,e2,e3 ----------
// PRED chain erodes in logit domain (monotone sigmoid applied at writes).
// DICE: also accumulates sum(p1), sum(oh), sum(oh*p1) -> acc[0..2].
template<int SRC, bool DICE>
__global__ void __launch_bounds__(512)
erode123_kernel(float* ebase, long long zstride, int b0, int bstep,
                const float* __restrict__ yp, const int* __restrict__ yt,
                double* __restrict__ acc) {
    const int zc = blockIdx.z;
    float* e1 = ebase + (size_t)((long long)zc * zstride);
    float* e2 = e1 + VOL;
    float* e3 = e2 + VOL;
    const int b = b0 + zc * bstep;

    const int x = threadIdx.x, y = threadIdx.y;
    const int tw = blockIdx.x % ETW, th = blockIdx.x / ETW;
    const int slab = blockIdx.y;
    const int w = tw * EOX + x - 3, h = th * EOY + y - 3;
    const bool cv = (w >= 0 && w < WD && h >= 0 && h < HD);
    const int z0 = slab * SLABZ, z1 = z0 + SLABZ;
    const bool inner = (x >= 3 && x < 3 + EOX && y >= 3 && y < 3 + EOY && w < WD && h < HD);

    __shared__ float sm[TSY][TSX], e1m[TSY][TSX], e2m[TSY][TSX];

    float sA = PINF, sB = PINF, c1p = PINF;
    float e1a = PINF, e1b = PINF, c2p = PINF;
    float e2a = PINF, e2b = PINF, c3p = PINF;
    float ds_p = 0.f, ds_o = 0.f, ds_i = 0.f;

    const float* pb = yp + (size_t)b * (2 * (size_t)VOL);
    const int*   tb = yt + (size_t)b * VOL;

    for (int Z = z0 - 3; Z <= z1 + 2; ++Z) {
        const bool zv = (Z >= 0 && Z < DD);
        const bool lv = cv && zv;
        const int idx = (Z * HD + h) * WD + w;
        float s = PINF;
        if constexpr (SRC == SRC_PRED) {
            if (lv) s = pb[(size_t)VOL + idx] - pb[idx];      // logit = x1 - x0
        } else {
            if (lv) s = (tb[idx] == 1) ? 1.f : 0.f;
        }
        if constexpr (DICE) {
            if (inner && zv && Z >= z0 && Z < z1) {
                float p1 = 1.f / (1.f + __expf(-s));
                ds_p += p1;
                if (tb[idx] == 1) { ds_o += 1.f; ds_i += p1; }
            }
        }
        // stage 1: s -> e1
        float a0 = fmin3(__shfl_up(s, 1, 32), s, __shfl_down(s, 1, 32));
        sm[y][x] = s;
        __syncthreads();
        float c1 = fmin3(a0, (y > 0) ? sm[y-1][x] : PINF, (y < TSY-1) ? sm[y+1][x] : PINF);
        float e1c = fmin3(c1p, sA, s);                       // e1(Z-1)
        int zo1 = Z - 1;
        if (inner && zo1 >= z0 && zo1 < z1) e1[((size_t)zo1 * HD + h) * WD + w] = xform<SRC>(e1c);
        // stage 2: e1 -> e2
        float a1 = fmin3(__shfl_up(e1c, 1, 32), e1c, __shfl_down(e1c, 1, 32));
        e1m[y][x] = e1c;
        __syncthreads();
        float c2 = fmin3(a1, (y > 0) ? e1m[y-1][x] : PINF, (y < TSY-1) ? e1m[y+1][x] : PINF);
        float e2c = fmin3(c2p, e1a, e1c);                    // e2(Z-2)
        int zo2 = Z - 2;
        if (inner && zo2 >= z0 && zo2 < z1) e2[((size_t)zo2 * HD + h) * WD + w] = xform<SRC>(e2c);
        // stage 3: e2 -> e3
        float a2 = fmin3(__shfl_up(e2c, 1, 32), e2c, __shfl_down(e2c, 1, 32));
        e2m[y][x] = e2c;
        __syncthreads();
        float c3 = fmin3(a2, (y > 0) ? e2m[y-1][x] : PINF, (y < TSY-1) ? e2m[y+1][x] : PINF);
        float e3c = fmin3(c3p, e2a, e2c);                    // e3(Z-3)
        int zo3 = Z - 3;
        if (inner && zo3 >= z0 && zo3 < z1) e3[((size_t)zo3 * HD + h) * WD + w] = xform<SRC>(e3c);
        // rotate rings
        sA = sB; sB = s; c1p = c1;
        e1a = e1b; e1b = e1c; c2p = c2;
        e2a = e2b; e2b = e2c; c3p = c3;
    }

    if constexpr (DICE) {
        for (int off = 32; off > 0; off >>= 1) {
            ds_p += __shfl_down(ds_p, off);
            ds_o += __shfl_down(ds_o, off);
            ds_i += __shfl_down(ds_i, off);
        }
        __shared__ float r0[8], r1[8], r2[8];
        int tid = y * TSX + x, wid = tid >> 6, lane = tid & 63;
        if (lane == 0) { r0[wid] = ds_p; r1[wid] = ds_o; r2[wid] = ds_i; }
        __syncthreads();
        if (tid == 0) {
            float t0 = 0.f, t1 = 0.f, t2 = 0.f;
            for (int i = 0; i < 8; ++i) { t0 += r0[i]; t1 += r1[i]; t2 += r2[i]; }
            atomicAdd(acc + 0, (double)t0);
            atomicAdd(acc + 1, (double)t1);
            atomicAdd(acc + 2, (double)t2);
        }
    }
}

// ---------- fused cl-dice kernel: dilates of e1..e4 (e4 on the fly), skel sums ----------
template<int SSRC, int WSRC>
__global__ void __launch_bounds__(512)
fused_cldice_kernel(const float* ebase, long long zstride, int b0, int bstep,
                    const float* __restrict__ yp, const int* __restrict__ yt,
                    double* __restrict__ acc) {
    const int zc = blockIdx.z;
    const float* e1v = ebase + (size_t)((long long)zc * zstride);
    const float* e2v = e1v + VOL;
    const float* e3v = e2v + VOL;
    const int b = b0 + zc * bstep;

    const int x = threadIdx.x, y = threadIdx.y;
    const int tw = blockIdx.x % 7;             // 7 W-tiles of 28 (overhang clipped)
    const int th = blockIdx.x / 7;
    const int slab = blockIdx.y;
    const int w = tw * OSX + x - 2;
    const int h = th * OSY + y - 2;
    const bool cv = (w >= 0 && w < WD && h >= 0 && h < HD);
    const int z0 = slab * SLABZ, z1 = z0 + SLABZ;
    const bool inner = (x >= 2 && x < 2 + OSX && y >= 2 && y < 2 + OSY && w < WD && h < HD);

    __shared__ float rm0[TSY][TSX], rm1[TSY][TSX], rm2[TSY][TSX],
                     e3p[TSY][TSX], rm3[TSY][TSX];

    float m20a = NINF, m20b = NINF, m21a = NINF, m21b = NINF;
    float m22a = NINF, m22b = NINF, m23a = NINF, m23b = NINF;
    float e3a = PINF, e3b = PINF;     // own-column e3 (min-sentineled), planes Z-2, Z-1
    float ce3p = PINF;                // c_e3[Z-1]
    float e1p = 0.f, e2p = 0.f;       // own e1,e2 at plane Z-1
    float pap = 1.f;                  // (1-d0)(1-d1)(1-d2) at Z-2
    float sum_s = 0.f, sum_sw = 0.f;

    for (int Z = z0 - 2; Z <= z1 + 1; ++Z) {
        const bool zv = (Z >= 0 && Z < DD);
        const bool lv = cv && zv;
        const int idx = (Z * HD + h) * WD + w;
        float g1  = lv ? e1v[idx] : NINF;
        float g2  = lv ? e2v[idx] : NINF;
        float g3r = lv ? e3v[idx] : 0.f;
        float g3x = lv ? g3r : NINF;      // dilate path
        float g3n = lv ? g3r : PINF;      // erode path

        __syncthreads();
        float r0 = fmax3(__shfl_up(g1, 1, 32),  g1,  __shfl_down(g1, 1, 32));
        float r1 = fmax3(__shfl_up(g2, 1, 32),  g2,  __shfl_down(g2, 1, 32));
        float r2 = fmax3(__shfl_up(g3x, 1, 32), g3x, __shfl_down(g3x, 1, 32));
        float rn = fmin3(__shfl_up(g3n, 1, 32), g3n, __shfl_down(g3n, 1, 32));
        rm0[y][x] = r0; rm1[y][x] = r1; rm2[y][x] = r2; e3p[y][x] = g3n;
        __syncthreads();
        float m20c = fmax3(r0, (y > 0) ? rm0[y-1][x] : NINF, (y < TSY-1) ? rm0[y+1][x] : NINF);
        float m21c = fmax3(r1, (y > 0) ? rm1[y-1][x] : NINF, (y < TSY-1) ? rm1[y+1][x] : NINF);
        float m22c = fmax3(r2, (y > 0) ? rm2[y-1][x] : NINF, (y < TSY-1) ? rm2[y+1][x] : NINF);
        float ce3  = fmin3(rn, (y > 0) ? e3p[y-1][x] : PINF, (y < TSY-1) ? e3p[y+1][x] : PINF);
        float e4 = fmin3(ce3p, e3a, g3n);         // e4(Z-1)
        const bool zv1 = (Z-1 >= 0 && Z-1 < DD);
        float e4x = (cv && zv1) ? e4 : NINF;
        float r3 = fmax3(__shfl_up(e4x, 1, 32), e4x, __shfl_down(e4x, 1, 32));
        rm3[y][x] = r3;
        __syncthreads();
        float m23c = fmax3(r3, (y > 0) ? rm3[y-1][x] : NINF, (y < TSY-1) ? rm3[y+1][x] : NINF);

        float pac = 1.f;
        const int zo1 = Z - 1;
        if (inner && zo1 >= z0 && zo1 < z1) {
            float d0 = fmax3(m20a, m20b, m20c);
            float d1 = fmax3(m21a, m21b, m21c);
            float d2 = fmax3(m22a, m22b, m22c);
            float s  = ld_center<SSRC>(yp, yt, b, (zo1 * HD + h) * WD + w);
            float t0 = fmaxf(s   - d0, 0.f);
            float t1 = fmaxf(e1p - d1, 0.f);
            float t2 = fmaxf(e2p - d2, 0.f);
            pac = (1.f - t0) * (1.f - t1) * (1.f - t2);
        }
        const int zo2 = Z - 2;
        if (inner && zo2 >= z0 && zo2 < z1) {
            float d3 = fmax3(m23a, m23b, m23c);
            float t3 = fmaxf(e3a - d3, 0.f);
            float skel = 1.f - pap * (1.f - t3);
            float wgt = ld_center<WSRC>(yp, yt, b, (zo2 * HD + h) * WD + w);
            sum_s  += skel;
            sum_sw += skel * wgt;
        }
        m20a = m20b; m20b = m20c;  m21a = m21b; m21b = m21c;
        m22a = m22b; m22b = m22c;  m23a = m23b; m23b = m23c;
        e3a = e3b;  e3b = g3n;
        ce3p = ce3;
        e1p = g1;   e2p = g2;
        pap = pac;
    }

    for (int off = 32; off > 0; off >>= 1) {
        sum_s  += __shfl_down(sum_s,  off);
        sum_sw += __shfl_down(sum_sw, off);
    }
    __shared__ float s0[8], s1[8];
    int tid = y * TSX + x;
    int wid = tid >> 6, lane = tid & 63;
    if (lane == 0) { s0[wid] = sum_s; s1[wid] = sum_sw; }
    __syncthreads();
    if (tid == 0) {
        float t0 = 0.f, t1 = 0.f;
        for (int i = 0; i < 8; ++i) { t0 += s0[i]; t1 += s1[i]; }
        atomicAdd(acc + 0, (double)t0);
        atomicAdd(acc + 1, (double)t1);
    }
}

__global__ void zero_accum_kernel(double* acc) {
    if (threadIdx.x < 8) acc[threadIdx.x] = 0.0;
}

__global__ void finalize_kernel(const double* __restrict__ acc, float* __restrict__ out) {
    double sum_p = acc[0], sum_oh = acc[1], inter = acc[2];
    double sp_s = acc[3], sp_w = acc[4];   // skel_pred: sum, sum*oh
    double st_s = acc[5], st_w = acc[6];   // skel_true: sum, sum*p
    double dice  = 1.0 - (2.0 * inter + 1.0) / (sum_oh + sum_p + 1.0);
    double tprec = (sp_w + 1.0) / (sp_s + 1.0);
    double tsens = (st_w + 1.0) / (st_s + 1.0);
    double cl    = 1.0 - 2.0 * (tprec * tsens) / (tprec + tsens);
    out[0] = (float)(dice + cl);
}

extern "C" void kernel_launch(void* const* d_in, const int* in_sizes, int n_in,
                              void* d_out, int out_size, void* d_ws, size_t ws_size,
                              hipStream_t stream) {
    const float* y_pred = (const float*)d_in[0];
    const int*   y_true = (const int*)d_in[1];
    float* out = (float*)d_out;

    char* ws = (char*)d_ws;
    double* acc = (double*)ws;                     // 8 doubles
    float* vols = (float*)(ws + 256);
    const long long CS = 3LL * VOL;                // floats per chain (e1,e2,e3)

    const bool wide = ws_size >= (size_t)256 + 12ull * (size_t)VOL * 4ull;

    zero_accum_kernel<<<1, 64, 0, stream>>>(acc);

    dim3 tb(TSX, TSY);                             // 512 threads
    if (wide) {
        // chains: c = 2*b + kind; pred chains at vols + 2*b*CS, true at +CS
        dim3 eg(ETW * ETH, NSLAB, 2);
        erode123_kernel<SRC_PRED, true ><<<eg, tb, 0, stream>>>(vols,      2*CS, 0, 1, y_pred, y_true, acc);
        erode123_kernel<SRC_TRUE, false><<<eg, tb, 0, stream>>>(vols + CS, 2*CS, 0, 1, y_pred, y_true, acc);
        dim3 fg(7 * (HD / OSY), NSLAB, 2);
        fused_cldice_kernel<SRC_PRED, SRC_TRUE><<<fg, tb, 0, stream>>>(vols,      2*CS, 0, 1, y_pred, y_true, acc + 3);
        fused_cldice_kernel<SRC_TRUE, SRC_PRED><<<fg, tb, 0, stream>>>(vols + CS, 2*CS, 0, 1, y_pred, y_true, acc + 5);
    } else {
        dim3 eg(ETW * ETH, NSLAB, 1);
        dim3 fg(7 * (HD / OSY), NSLAB, 1);
        for (int b = 0; b < 2; ++b) {
            erode123_kernel<SRC_PRED, true ><<<eg, tb, 0, stream>>>(vols, 0, b, 0, y_pred, y_true, acc);
            fused_cldice_kernel<SRC_PRED, SRC_TRUE><<<fg, tb, 0, stream>>>(vols, 0, b, 0, y_pred, y_true, acc + 3);
            erode123_kernel<SRC_TRUE, false><<<eg, tb, 0, stream>>>(vols, 0, b, 0, y_pred, y_true, acc);
            fused_cldice_kernel<SRC_TRUE, SRC_PRED><<<fg, tb, 0, stream>>>(vols, 0, b, 0, y_pred, y_true, acc + 5);
        }
    }

    finalize_kernel<<<1, 1, 0, stream>>>(acc, out);
}

// Round 4
// 300.345 us; speedup vs baseline: 4.3804x; 1.2191x over previous
//
#include <hip/hip_runtime.h>
#include <hip/hip_fp16.h>
#include <math.h>

// Problem geometry (fixed per reference setup_inputs)
#define WD 192
#define HD 192
#define DD 96
#define HW (HD*WD)
#define VOL (DD*HD*WD)          // 3,538,944 voxels per volume

#define PINF INFINITY
#define NINF (-INFINITY)

typedef unsigned int u32;
#define ONE1 0x3C00u            // fp16 1.0 (values are in [0,1]; min-pad with 1.0 == +inf pad)
#define ONE2 0x3C003C00u

#define W8N (WD/8)              // 24 row-octets per row
#define D2N (DD/2)              // 48 z-pairs
#define ETHREADS 256
#define EBLOCKS ((W8N*HD*D2N)/ETHREADS)   // 864, exact

__device__ __forceinline__ float fmin3(float a, float b, float c) { return fminf(a, fminf(b, c)); }
__device__ __forceinline__ float fmax3(float a, float b, float c) { return fmaxf(a, fmaxf(b, c)); }
__device__ __forceinline__ float sigf(float l) { return 1.0f / (1.0f + __expf(-l)); }

// packed 2xfp16 min via u16 ordering (valid: all values >= 0, no NaN)
__device__ __forceinline__ u32 h2min(u32 a, u32 b) {
    u32 lo = ((a & 0xffffu) < (b & 0xffffu)) ? (a & 0xffffu) : (b & 0xffffu);
    u32 hi = ((a >> 16) < (b >> 16)) ? (a & 0xffff0000u) : (b & 0xffff0000u);
    return lo | hi;
}
__device__ __forceinline__ uint4 min44(uint4 a, uint4 b) {
    return make_uint4(h2min(a.x,b.x), h2min(a.y,b.y), h2min(a.z,b.z), h2min(a.w,b.w));
}
__device__ __forceinline__ uint4 ldrow16(const __half* p, bool v) {
    if (v) return *(const uint4*)p;
    return make_uint4(ONE2, ONE2, ONE2, ONE2);
}
// shifted views of an 8-half row: element j <- row[j-1] (shl) / row[j+1] (shr)
__device__ __forceinline__ uint4 shl8(uint4 r, u32 lh) {
    return make_uint4((r.x << 16) | (lh & 0xffffu), (r.y << 16) | (r.x >> 16),
                      (r.z << 16) | (r.y >> 16),    (r.w << 16) | (r.z >> 16));
}
__device__ __forceinline__ uint4 shr8(uint4 r, u32 rh) {
    return make_uint4((r.x >> 16) | (r.y << 16), (r.y >> 16) | (r.z << 16),
                      (r.z >> 16) | (r.w << 16), (r.w >> 16) | (rh << 16));
}
__device__ __forceinline__ u32 pack2(float a, float b) {
    return (u32)__half_as_ushort(__float2half_rn(a)) |
           ((u32)__half_as_ushort(__float2half_rn(b)) << 16);
}

// fp32 row loaders for e1 sources
__device__ __forceinline__ void ldrow_pred(const float* pb, int idx, float* r) {
    float4 a0 = *(const float4*)(pb + idx);
    float4 a1 = *(const float4*)(pb + idx + 4);
    float4 b0 = *(const float4*)(pb + (size_t)VOL + idx);
    float4 b1 = *(const float4*)(pb + (size_t)VOL + idx + 4);
    r[0]=b0.x-a0.x; r[1]=b0.y-a0.y; r[2]=b0.z-a0.z; r[3]=b0.w-a0.w;
    r[4]=b1.x-a1.x; r[5]=b1.y-a1.y; r[6]=b1.z-a1.z; r[7]=b1.w-a1.w;
}
__device__ __forceinline__ void ldrow_true(const int* tb, int idx, float* r) {
    int4 a0 = *(const int4*)(tb + idx);
    int4 a1 = *(const int4*)(tb + idx + 4);
    r[0]=(a0.x==1)?1.f:0.f; r[1]=(a0.y==1)?1.f:0.f; r[2]=(a0.z==1)?1.f:0.f; r[3]=(a0.w==1)?1.f:0.f;
    r[4]=(a1.x==1)?1.f:0.f; r[5]=(a1.y==1)?1.f:0.f; r[6]=(a1.z==1)?1.f:0.f; r[7]=(a1.w==1)?1.f:0.f;
}
__device__ __forceinline__ void infrow(float* r) {
    #pragma unroll
    for (int j = 0; j < 8; ++j) r[j] = PINF;
}

// ---------- e1 pass: streaming erode7 of source (logit domain for pred), fp16 out ----------
// z-coarsen x2, 8-wide. kind 0 = pred (+ dice sums), kind 1 = true.
__global__ void __launch_bounds__(256)
e1_kernel(__half* ebase, long long cstride, int b0, int bmask, int kshift,
          const float* __restrict__ yp, const int* __restrict__ yt,
          double* __restrict__ acc) {
    const int zc = blockIdx.z;
    const int kind = (zc >> kshift) & 1;
    const int b = b0 + (zc & bmask);
    __half* e1 = ebase + (size_t)zc * (size_t)cstride;

    const int i  = blockIdx.x * 256 + threadIdx.x;
    const int w8 = i % W8N;
    const int h  = (i / W8N) % HD;
    const int d2 = i / (W8N * HD);
    const int z  = d2 * 2;
    const int idx = (z * HD + h) * WD + w8 * 8;

    const float* pb = yp + (size_t)b * (2 * (size_t)VOL);
    const int*   tb = yt + (size_t)b * (size_t)VOL;

    float c0[8], c1[8], zm[8], zp[8], u0[8], u1[8], dn0[8], dn1[8];
    float lb0, lb1, rb0, rb1;

    if (kind == 0) {
        ldrow_pred(pb, idx, c0);  ldrow_pred(pb, idx + HW, c1);
        if (z > 0) ldrow_pred(pb, idx - HW, zm); else infrow(zm);
        if (z + 2 < DD) ldrow_pred(pb, idx + 2*HW, zp); else infrow(zp);
        if (h > 0) { ldrow_pred(pb, idx - WD, u0); ldrow_pred(pb, idx + HW - WD, u1); }
        else { infrow(u0); infrow(u1); }
        if (h < HD-1) { ldrow_pred(pb, idx + WD, dn0); ldrow_pred(pb, idx + HW + WD, dn1); }
        else { infrow(dn0); infrow(dn1); }
        lb0 = (w8 > 0) ? pb[(size_t)VOL + idx - 1] - pb[idx - 1] : PINF;
        lb1 = (w8 > 0) ? pb[(size_t)VOL + idx + HW - 1] - pb[idx + HW - 1] : PINF;
        rb0 = (w8 < W8N-1) ? pb[(size_t)VOL + idx + 8] - pb[idx + 8] : PINF;
        rb1 = (w8 < W8N-1) ? pb[(size_t)VOL + idx + HW + 8] - pb[idx + HW + 8] : PINF;
    } else {
        ldrow_true(tb, idx, c0);  ldrow_true(tb, idx + HW, c1);
        if (z > 0) ldrow_true(tb, idx - HW, zm); else infrow(zm);
        if (z + 2 < DD) ldrow_true(tb, idx + 2*HW, zp); else infrow(zp);
        if (h > 0) { ldrow_true(tb, idx - WD, u0); ldrow_true(tb, idx + HW - WD, u1); }
        else { infrow(u0); infrow(u1); }
        if (h < HD-1) { ldrow_true(tb, idx + WD, dn0); ldrow_true(tb, idx + HW + WD, dn1); }
        else { infrow(dn0); infrow(dn1); }
        lb0 = (w8 > 0) ? ((tb[idx-1]==1)?1.f:0.f) : PINF;
        lb1 = (w8 > 0) ? ((tb[idx+HW-1]==1)?1.f:0.f) : PINF;
        rb0 = (w8 < W8N-1) ? ((tb[idx+8]==1)?1.f:0.f) : PINF;
        rb1 = (w8 < W8N-1) ? ((tb[idx+HW+8]==1)?1.f:0.f) : PINF;
    }

    float o0[8], o1[8];
    #pragma unroll
    for (int j = 0; j < 8; ++j) {
        float l0 = (j == 0) ? lb0 : c0[j-1];
        float r0 = (j == 7) ? rb0 : c0[j+1];
        float l1 = (j == 0) ? lb1 : c1[j-1];
        float r1 = (j == 7) ? rb1 : c1[j+1];
        o0[j] = fminf(fmin3(l0, c0[j], r0), fmin3(fminf(u0[j], dn0[j]), zm[j], c1[j]));
        o1[j] = fminf(fmin3(l1, c1[j], r1), fmin3(fminf(u1[j], dn1[j]), c0[j], zp[j]));
    }

    uint4 q0, q1;
    if (kind == 0) {
        q0 = make_uint4(pack2(sigf(o0[0]),sigf(o0[1])), pack2(sigf(o0[2]),sigf(o0[3])),
                        pack2(sigf(o0[4]),sigf(o0[5])), pack2(sigf(o0[6]),sigf(o0[7])));
        q1 = make_uint4(pack2(sigf(o1[0]),sigf(o1[1])), pack2(sigf(o1[2]),sigf(o1[3])),
                        pack2(sigf(o1[4]),sigf(o1[5])), pack2(sigf(o1[6]),sigf(o1[7])));
    } else {
        q0 = make_uint4(pack2(o0[0],o0[1]), pack2(o0[2],o0[3]), pack2(o0[4],o0[5]), pack2(o0[6],o0[7]));
        q1 = make_uint4(pack2(o1[0],o1[1]), pack2(o1[2],o1[3]), pack2(o1[4],o1[5]), pack2(o1[6],o1[7]));
    }
    *(uint4*)(e1 + idx) = q0;
    *(uint4*)(e1 + idx + HW) = q1;

    // ---- fused dice sums (pred chains only): sum(p1), sum(oh), sum(oh*p1) ----
    if (kind == 0) {
        float ds_p = 0.f, ds_o = 0.f, ds_i = 0.f;
        int4 t00 = *(const int4*)(tb + idx);
        int4 t01 = *(const int4*)(tb + idx + 4);
        int4 t10 = *(const int4*)(tb + idx + HW);
        int4 t11 = *(const int4*)(tb + idx + HW + 4);
        int tv0[8] = {t00.x,t00.y,t00.z,t00.w,t01.x,t01.y,t01.z,t01.w};
        int tv1[8] = {t10.x,t10.y,t10.z,t10.w,t11.x,t11.y,t11.z,t11.w};
        #pragma unroll
        for (int j = 0; j < 8; ++j) {
            float p0 = sigf(c0[j]), p1 = sigf(c1[j]);
            ds_p += p0 + p1;
            if (tv0[j] == 1) { ds_o += 1.f; ds_i += p0; }
            if (tv1[j] == 1) { ds_o += 1.f; ds_i += p1; }
        }
        #pragma unroll
        for (int off = 32; off > 0; off >>= 1) {
            ds_p += __shfl_down(ds_p, off);
            ds_o += __shfl_down(ds_o, off);
            ds_i += __shfl_down(ds_i, off);
        }
        __shared__ float sA[4], sB[4], sC[4];
        int tid = threadIdx.x, wid = tid >> 6, lane = tid & 63;
        if (lane == 0) { sA[wid] = ds_p; sB[wid] = ds_o; sC[wid] = ds_i; }
        __syncthreads();
        if (tid == 0) {
            float t0 = sA[0]+sA[1]+sA[2]+sA[3];
            float t1 = sB[0]+sB[1]+sB[2]+sB[3];
            float t2 = sC[0]+sC[1]+sC[2]+sC[3];
            atomicAdd(acc + 0, (double)t0);
            atomicAdd(acc + 1, (double)t1);
            atomicAdd(acc + 2, (double)t2);
        }
    }
}

// ---------- e2/e3 pass: streaming erode7, fp16 -> fp16, packed min ----------
__global__ void __launch_bounds__(256)
e23_kernel(__half* base, long long cstride, long long inoff, long long outoff) {
    const int zc = blockIdx.z;
    const __half* src = base + (size_t)zc * (size_t)cstride + (size_t)inoff;
    __half* dst = base + (size_t)zc * (size_t)cstride + (size_t)outoff;

    const int i  = blockIdx.x * 256 + threadIdx.x;
    const int w8 = i % W8N;
    const int h  = (i / W8N) % HD;
    const int d2 = i / (W8N * HD);
    const int z  = d2 * 2;
    const int idx = (z * HD + h) * WD + w8 * 8;

    uint4 c0 = *(const uint4*)(src + idx);
    uint4 c1 = *(const uint4*)(src + idx + HW);
    uint4 zm  = ldrow16(src + idx - HW, z > 0);
    uint4 zp  = ldrow16(src + idx + 2*HW, z + 2 < DD);
    uint4 u0  = ldrow16(src + idx - WD, h > 0);
    uint4 u1  = ldrow16(src + idx + HW - WD, h > 0);
    uint4 dn0 = ldrow16(src + idx + WD, h < HD - 1);
    uint4 dn1 = ldrow16(src + idx + HW + WD, h < HD - 1);
    const unsigned short* ss = (const unsigned short*)src;
    u32 l0 = (w8 > 0) ? ss[idx - 1] : ONE1;
    u32 l1 = (w8 > 0) ? ss[idx + HW - 1] : ONE1;
    u32 r0 = (w8 < W8N-1) ? ss[idx + 8] : ONE1;
    u32 r1 = (w8 < W8N-1) ? ss[idx + HW + 8] : ONE1;

    uint4 wm0 = min44(min44(shl8(c0, l0), c0), shr8(c0, r0));
    uint4 wm1 = min44(min44(shl8(c1, l1), c1), shr8(c1, r1));
    uint4 o0 = min44(min44(wm0, u0), min44(dn0, min44(zm, c1)));
    uint4 o1 = min44(min44(wm1, u1), min44(dn1, min44(c0, zp)));
    *(uint4*)(dst + idx) = o0;
    *(uint4*)(dst + idx + HW) = o1;
}

// ---------- fused cl-dice: dilates of e1..e4 (e4 on the fly), skel product, sums ----------
#define TSX 32
#define TSY 16
#define OSX 28
#define OSY 12
#define NSLAB 8
#define SLABZ (DD/NSLAB)

__global__ void __launch_bounds__(512)
fused_cldice_kernel(const __half* ebase, long long cstride, int b0, int bmask, int kshift,
                    const float* __restrict__ yp, const int* __restrict__ yt,
                    double* __restrict__ acc) {
    const int zc = blockIdx.z;
    const int kind = (zc >> kshift) & 1;   // 0: skel(pred), weight=oh; 1: skel(true), weight=p
    const int b = b0 + (zc & bmask);
    const __half* e1v = ebase + (size_t)zc * (size_t)cstride;
    const __half* e2v = e1v + VOL;
    const __half* e3v = e2v + VOL;
    const float* pb = yp + (size_t)b * (2 * (size_t)VOL);
    const int*   tb = yt + (size_t)b * (size_t)VOL;

    const int x = threadIdx.x, y = threadIdx.y;
    const int tw = blockIdx.x % 7, th = blockIdx.x / 7;
    const int slab = blockIdx.y;
    const int w = tw * OSX + x - 2, h = th * OSY + y - 2;
    const bool cv = (w >= 0 && w < WD && h >= 0 && h < HD);
    const int z0 = slab * SLABZ, z1 = z0 + SLABZ;
    const bool inner = (x >= 2 && x < 2 + OSX && y >= 2 && y < 2 + OSY && w < WD && h < HD);

    __shared__ float rm0[2][TSY][TSX], rm1[2][TSY][TSX], rm2[2][TSY][TSX],
                     e3s[2][TSY][TSX], rm3[2][TSY][TSX];

    float m20a = NINF, m20b = NINF, m21a = NINF, m21b = NINF;
    float m22a = NINF, m22b = NINF, m23a = NINF, m23b = NINF;
    float e3a = PINF, e3b = PINF;     // own-column e3, planes Z-2, Z-1
    float ce3p = PINF;                // in-plane cross-min of e3 at Z-1
    float e1p = 0.f, e2p = 0.f;       // own e1,e2 at Z-1
    float pap = 1.f;                  // (1-d0)(1-d1)(1-d2) at Z-2
    float sum_s = 0.f, sum_sw = 0.f;
    int pbuf = 0;

    for (int Z = z0 - 2; Z <= z1 + 1; ++Z, pbuf ^= 1) {
        const bool zv = (Z >= 0 && Z < DD);
        const bool lv = cv && zv;
        const int idx = (Z * HD + h) * WD + w;
        float g1  = lv ? __half2float(e1v[idx]) : NINF;
        float g2  = lv ? __half2float(e2v[idx]) : NINF;
        float g3r = lv ? __half2float(e3v[idx]) : 0.f;
        float g3x = lv ? g3r : NINF;      // dilate path
        float g3n = lv ? g3r : PINF;      // erode path

        float r0 = fmax3(__shfl_up(g1, 1, 32),  g1,  __shfl_down(g1, 1, 32));
        float r1 = fmax3(__shfl_up(g2, 1, 32),  g2,  __shfl_down(g2, 1, 32));
        float r2 = fmax3(__shfl_up(g3x, 1, 32), g3x, __shfl_down(g3x, 1, 32));
        float rn = fmin3(__shfl_up(g3n, 1, 32), g3n, __shfl_down(g3n, 1, 32));
        rm0[pbuf][y][x] = r0; rm1[pbuf][y][x] = r1; rm2[pbuf][y][x] = r2; e3s[pbuf][y][x] = g3n;
        __syncthreads();
        float m20c = fmax3(r0, (y > 0) ? rm0[pbuf][y-1][x] : NINF, (y < TSY-1) ? rm0[pbuf][y+1][x] : NINF);
        float m21c = fmax3(r1, (y > 0) ? rm1[pbuf][y-1][x] : NINF, (y < TSY-1) ? rm1[pbuf][y+1][x] : NINF);
        float m22c = fmax3(r2, (y > 0) ? rm2[pbuf][y-1][x] : NINF, (y < TSY-1) ? rm2[pbuf][y+1][x] : NINF);
        float ce3  = fmin3(rn, (y > 0) ? e3s[pbuf][y-1][x] : PINF, (y < TSY-1) ? e3s[pbuf][y+1][x] : PINF);
        float e4 = fmin3(ce3p, e3a, g3n);          // e4(Z-1)
        const bool zv1 = (Z-1 >= 0 && Z-1 < DD);
        float e4x = (cv && zv1) ? e4 : NINF;
        float r3 = fmax3(__shfl_up(e4x, 1, 32), e4x, __shfl_down(e4x, 1, 32));
        rm3[pbuf][y][x] = r3;
        __syncthreads();
        float m23c = fmax3(r3, (y > 0) ? rm3[pbuf][y-1][x] : NINF, (y < TSY-1) ? rm3[pbuf][y+1][x] : NINF);

        float pac = 1.f;
        const int zo1 = Z - 1;
        if (inner && zo1 >= z0 && zo1 < z1) {
            float d0 = fmax3(m20a, m20b, m20c);
            float d1 = fmax3(m21a, m21b, m21c);
            float d2 = fmax3(m22a, m22b, m22c);
            const int cidx = (zo1 * HD + h) * WD + w;
            float s = (kind == 0) ? sigf(pb[(size_t)VOL + cidx] - pb[cidx])
                                  : ((tb[cidx] == 1) ? 1.f : 0.f);
            float t0 = fmaxf(s   - d0, 0.f);
            float t1 = fmaxf(e1p - d1, 0.f);
            float t2 = fmaxf(e2p - d2, 0.f);
            pac = (1.f - t0) * (1.f - t1) * (1.f - t2);
        }
        const int zo2 = Z - 2;
        if (inner && zo2 >= z0 && zo2 < z1) {
            float d3 = fmax3(m23a, m23b, m23c);
            float t3 = fmaxf(e3a - d3, 0.f);
            float skel = 1.f - pap * (1.f - t3);
            const int cidx = (zo2 * HD + h) * WD + w;
            float wgt = (kind == 1) ? sigf(pb[(size_t)VOL + cidx] - pb[cidx])
                                    : ((tb[cidx] == 1) ? 1.f : 0.f);
            sum_s  += skel;
            sum_sw += skel * wgt;
        }
        m20a = m20b; m20b = m20c;  m21a = m21b; m21b = m21c;
        m22a = m22b; m22b = m22c;  m23a = m23b; m23b = m23c;
        e3a = e3b;  e3b = g3n;
        ce3p = ce3;
        e1p = g1;   e2p = g2;
        pap = pac;
    }

    #pragma unroll
    for (int off = 32; off > 0; off >>= 1) {
        sum_s  += __shfl_down(sum_s,  off);
        sum_sw += __shfl_down(sum_sw, off);
    }
    __shared__ float s0[8], s1[8];
    int tid = y * TSX + x;
    int wid = tid >> 6, lane = tid & 63;
    if (lane == 0) { s0[wid] = sum_s; s1[wid] = sum_sw; }
    __syncthreads();
    if (tid == 0) {
        float t0 = 0.f, t1 = 0.f;
        for (int k = 0; k < 8; ++k) { t0 += s0[k]; t1 += s1[k]; }
        double* ac = acc + 3 + 2 * kind;
        atomicAdd(ac + 0, (double)t0);
        atomicAdd(ac + 1, (double)t1);
    }
}

__global__ void zero_accum_kernel(double* acc) {
    if (threadIdx.x < 8) acc[threadIdx.x] = 0.0;
}

__global__ void finalize_kernel(const double* __restrict__ acc, float* __restrict__ out) {
    double sum_p = acc[0], sum_oh = acc[1], inter = acc[2];
    double sp_s = acc[3], sp_w = acc[4];   // skel_pred: sum, sum*oh
    double st_s = acc[5], st_w = acc[6];   // skel_true: sum, sum*p
    double dice  = 1.0 - (2.0 * inter + 1.0) / (sum_oh + sum_p + 1.0);
    double tprec = (sp_w + 1.0) / (sp_s + 1.0);
    double tsens = (st_w + 1.0) / (st_s + 1.0);
    double cl    = 1.0 - 2.0 * (tprec * tsens) / (tprec + tsens);
    out[0] = (float)(dice + cl);
}

extern "C" void kernel_launch(void* const* d_in, const int* in_sizes, int n_in,
                              void* d_out, int out_size, void* d_ws, size_t ws_size,
                              hipStream_t stream) {
    const float* y_pred = (const float*)d_in[0];
    const int*   y_true = (const int*)d_in[1];
    float* out = (float*)d_out;

    char* ws = (char*)d_ws;
    double* acc = (double*)ws;                      // 8 doubles
    __half* vols = (__half*)(ws + 256);
    const long long CS = 3LL * VOL;                 // halfs per chain (e1,e2,e3)

    const bool wide = ws_size >= (size_t)256 + 4ull * (size_t)CS * 2ull;   // 85 MB

    zero_accum_kernel<<<1, 64, 0, stream>>>(acc);

    dim3 fblk(TSX, TSY);
    if (wide) {
        // chains: 0,1 = pred b=0,1 ; 2,3 = true b=0,1  (kind = zc>>1, b = zc&1)
        dim3 eg(EBLOCKS, 1, 4);
        dim3 fg(7 * (HD / OSY), NSLAB, 4);
        e1_kernel<<<eg, ETHREADS, 0, stream>>>(vols, CS, 0, 1, 1, y_pred, y_true, acc);
        e23_kernel<<<eg, ETHREADS, 0, stream>>>(vols, CS, 0,   VOL);     // e1 -> e2
        e23_kernel<<<eg, ETHREADS, 0, stream>>>(vols, CS, VOL, 2*VOL);   // e2 -> e3
        fused_cldice_kernel<<<fg, fblk, 0, stream>>>(vols, CS, 0, 1, 1, y_pred, y_true, acc);
    } else {
        // per-batch serial: chains 0 = pred, 1 = true (kind = zc&1, b fixed)
        dim3 eg(EBLOCKS, 1, 2);
        dim3 fg(7 * (HD / OSY), NSLAB, 2);
        for (int b = 0; b < 2; ++b) {
            e1_kernel<<<eg, ETHREADS, 0, stream>>>(vols, CS, b, 0, 0, y_pred, y_true, acc);
            e23_kernel<<<eg, ETHREADS, 0, stream>>>(vols, CS, 0,   VOL);
            e23_kernel<<<eg, ETHREADS, 0, stream>>>(vols, CS, VOL, 2*VOL);
            fused_cldice_kernel<<<fg, fblk, 0, stream>>>(vols, CS, b, 0, 0, y_pred, y_true, acc);
        }
    }

    finalize_kernel<<<1, 1, 0, stream>>>(acc, out);
}